// Round 2
// baseline (1203.219 us; speedup 1.0000x reference)
//
#include <hip/hip_runtime.h>
#include <hip/hip_bf16.h>

// ---------------- small utils ----------------

__global__ __launch_bounds__(256) void zero_ints(int* a, int na, int* b, int nb) {
    int i = blockIdx.x * blockDim.x + threadIdx.x;
    int st = gridDim.x * blockDim.x;
    for (int k = i; k < na; k += st) a[k] = 0;
    for (int k = i; k < nb; k += st) b[k] = 0;
}

// ---------------- binned CSR build ----------------
// um: dst in [0,20000), bucket width 32  -> 625 buckets
// mu: dst in [0,100000), bucket width 128 -> 782 buckets

#define NB_UM 625
#define NB_MU 782

__global__ __launch_bounds__(256) void bucket_hist(const int* __restrict__ dst_um,
                                                   const int* __restrict__ dst_mu,
                                                   int* __restrict__ bhist_um,
                                                   int* __restrict__ bhist_mu, int E) {
    __shared__ int h[NB_UM + NB_MU];
    for (int i = threadIdx.x; i < NB_UM + NB_MU; i += 256) h[i] = 0;
    __syncthreads();
    int st = gridDim.x * blockDim.x;
    int n4 = E >> 2;
    for (int i = blockIdx.x * blockDim.x + threadIdx.x; i < n4; i += st) {
        int4 d = ((const int4*)dst_um)[i];
        atomicAdd(&h[d.x >> 5], 1);
        atomicAdd(&h[d.y >> 5], 1);
        atomicAdd(&h[d.z >> 5], 1);
        atomicAdd(&h[d.w >> 5], 1);
        int4 e = ((const int4*)dst_mu)[i];
        atomicAdd(&h[NB_UM + (e.x >> 7)], 1);
        atomicAdd(&h[NB_UM + (e.y >> 7)], 1);
        atomicAdd(&h[NB_UM + (e.z >> 7)], 1);
        atomicAdd(&h[NB_UM + (e.w >> 7)], 1);
    }
    // tail
    for (int i = (n4 << 2) + blockIdx.x * blockDim.x + threadIdx.x; i < E; i += st) {
        atomicAdd(&h[dst_um[i] >> 5], 1);
        atomicAdd(&h[NB_UM + (dst_mu[i] >> 7)], 1);
    }
    __syncthreads();
    for (int i = threadIdx.x; i < NB_UM; i += 256)
        if (h[i]) atomicAdd(&bhist_um[i], h[i]);
    for (int i = threadIdx.x; i < NB_MU; i += 256)
        if (h[NB_UM + i]) atomicAdd(&bhist_mu[i], h[NB_UM + i]);
}

// single-block exclusive scan of NB (<=2048) values; writes boff[0..NB], bcur copy,
// and off[n] = E (CSR tail sentinel).
__global__ __launch_bounds__(256) void bucket_scan(const int* __restrict__ bhist,
                                                   int* __restrict__ boff,
                                                   int* __restrict__ bcur, int NB,
                                                   int* __restrict__ off, int n, int E) {
    __shared__ int sdata[256];
    int t = threadIdx.x;
    int v[8];
    int sum = 0;
#pragma unroll
    for (int i = 0; i < 8; i++) {
        int idx = t * 8 + i;
        int c = (idx < NB) ? bhist[idx] : 0;
        v[i] = sum;
        sum += c;
    }
    sdata[t] = sum;
    __syncthreads();
    for (int s = 1; s < 256; s <<= 1) {
        int y = (t >= s) ? sdata[t - s] : 0;
        __syncthreads();
        sdata[t] += y;
        __syncthreads();
    }
    int base = (t == 0) ? 0 : sdata[t - 1];
#pragma unroll
    for (int i = 0; i < 8; i++) {
        int idx = t * 8 + i;
        if (idx < NB) {
            int o = base + v[i];
            boff[idx] = o;
            bcur[idx] = o;
        }
    }
    if (t == 0) {
        boff[NB] = E;
        off[n] = E;
    }
}

// append packed (src | dst_local<<20) into bucket regions
__global__ __launch_bounds__(256) void bin2(const int* __restrict__ src_um,
                                            const int* __restrict__ dst_um,
                                            const int* __restrict__ src_mu,
                                            const int* __restrict__ dst_mu,
                                            int* __restrict__ bcur_um, int* __restrict__ bcur_mu,
                                            int* __restrict__ tmp_um, int* __restrict__ tmp_mu,
                                            int E) {
    int st = gridDim.x * blockDim.x;
    int n4 = E >> 2;
    for (int i = blockIdx.x * blockDim.x + threadIdx.x; i < n4; i += st) {
        int4 s = ((const int4*)src_um)[i];
        int4 d = ((const int4*)dst_um)[i];
        int p;
        p = atomicAdd(&bcur_um[d.x >> 5], 1); tmp_um[p] = s.x | ((d.x & 31) << 20);
        p = atomicAdd(&bcur_um[d.y >> 5], 1); tmp_um[p] = s.y | ((d.y & 31) << 20);
        p = atomicAdd(&bcur_um[d.z >> 5], 1); tmp_um[p] = s.z | ((d.z & 31) << 20);
        p = atomicAdd(&bcur_um[d.w >> 5], 1); tmp_um[p] = s.w | ((d.w & 31) << 20);
        int4 s2 = ((const int4*)src_mu)[i];
        int4 d2 = ((const int4*)dst_mu)[i];
        p = atomicAdd(&bcur_mu[d2.x >> 7], 1); tmp_mu[p] = s2.x | ((d2.x & 127) << 20);
        p = atomicAdd(&bcur_mu[d2.y >> 7], 1); tmp_mu[p] = s2.y | ((d2.y & 127) << 20);
        p = atomicAdd(&bcur_mu[d2.z >> 7], 1); tmp_mu[p] = s2.z | ((d2.z & 127) << 20);
        p = atomicAdd(&bcur_mu[d2.w >> 7], 1); tmp_mu[p] = s2.w | ((d2.w & 127) << 20);
    }
    for (int i = (n4 << 2) + blockIdx.x * blockDim.x + threadIdx.x; i < E; i += st) {
        int d = dst_um[i];
        int p = atomicAdd(&bcur_um[d >> 5], 1);
        tmp_um[p] = src_um[i] | ((d & 31) << 20);
        int d2 = dst_mu[i];
        int q = atomicAdd(&bcur_mu[d2 >> 7], 1);
        tmp_mu[q] = src_mu[i] | ((d2 & 127) << 20);
    }
}

// one workgroup per bucket: LDS per-dst count+scan+cursors, write off[] and csr[]
template <int W>
__global__ __launch_bounds__(256) void scatter_csr(const int* __restrict__ tmp,
                                                   const int* __restrict__ boff,
                                                   int* __restrict__ off,
                                                   int* __restrict__ csr, int n) {
    __shared__ int lcnt[W];
    __shared__ int lcur[W];
    int b = blockIdx.x;
    int t = threadIdx.x;
    int s = boff[b], e = boff[b + 1];
    if (t < W) lcnt[t] = 0;
    __syncthreads();
    for (int i = s + t; i < e; i += 256) atomicAdd(&lcnt[tmp[i] >> 20], 1);
    __syncthreads();
    if (t == 0) {
        int acc = s;
        for (int j = 0; j < W; j++) {
            lcur[j] = acc;
            acc += lcnt[j];
        }
    }
    __syncthreads();
    int base = b * W;
    if (t < W && base + t < n) off[base + t] = lcur[t];
    __syncthreads();
    for (int i = s + t; i < e; i += 256) {
        int v = tmp[i];
        int p = atomicAdd(&lcur[v >> 20], 1);
        csr[p] = v & 0xFFFFF;
    }
}

// ---------------- segment mean (gather, one wave per dst row) ----------------

template <int D>
__global__ __launch_bounds__(256) void agg_mean_v(const int* __restrict__ csr,
                                                  const int* __restrict__ off,
                                                  const float* __restrict__ x,
                                                  float* __restrict__ out, int nrows) {
    constexpr int LPE = D / 4;
    constexpr int GRP = 64 / LPE;
    int wave = (blockIdx.x * blockDim.x + threadIdx.x) >> 6;
    int lane = threadIdx.x & 63;
    int nwaves = (gridDim.x * blockDim.x) >> 6;
    int g = lane / LPE;
    int cl = lane % LPE;
    for (int row = wave; row < nrows; row += nwaves) {
        int s = off[row], e = off[row + 1];
        float4 acc = make_float4(0.f, 0.f, 0.f, 0.f);
        for (int k = s + g; k < e; k += GRP) {
            int idx = csr[k];
            const float4 v = *(const float4*)&x[(long)idx * D + cl * 4];
            acc.x += v.x; acc.y += v.y; acc.z += v.z; acc.w += v.w;
        }
        for (int m = LPE; m < 64; m <<= 1) {
            acc.x += __shfl_xor(acc.x, m, 64);
            acc.y += __shfl_xor(acc.y, m, 64);
            acc.z += __shfl_xor(acc.z, m, 64);
            acc.w += __shfl_xor(acc.w, m, 64);
        }
        if (g == 0) {
            float inv = 1.0f / fmaxf((float)(e - s), 1.0f);
            float4 r = make_float4(acc.x * inv, acc.y * inv, acc.z * inv, acc.w * inv);
            *(float4*)&out[(long)row * D + cl * 4] = r;
        }
    }
}

// ---------------- per-node dense: out = act(mean@Wl + b + xd@Wr) ----------------

template <int Dm, int Dd, bool RELU>
__global__ __launch_bounds__(256) void dense_node(const float* __restrict__ mean,
                                                  const float* __restrict__ xd,
                                                  const float* __restrict__ Wl,
                                                  const float* __restrict__ Wr,
                                                  const float* __restrict__ bias,
                                                  float* __restrict__ out, int n) {
    constexpr int H = 64;
    constexpr int ROWS = 16;
    __shared__ float sWl[Dm][H];
    __shared__ float sWr[Dd][H];
    __shared__ float sb[H];
    __shared__ float sm[ROWS][Dm];
    __shared__ float sx[ROWS][Dd];
    int t = threadIdx.x;
    for (int i = t; i < Dm * H; i += 256) sWl[i / H][i % H] = Wl[i];
    for (int i = t; i < Dd * H; i += 256) sWr[i / H][i % H] = Wr[i];
    if (t < H) sb[t] = bias[t];
    int rowbase = blockIdx.x * ROWS;
    for (int i = t; i < ROWS * Dm; i += 256) {
        int r = i / Dm, k = i % Dm;
        int gr = rowbase + r;
        sm[r][k] = (gr < n) ? mean[(long)gr * Dm + k] : 0.f;
    }
    for (int i = t; i < ROWS * Dd; i += 256) {
        int r = i / Dd, k = i % Dd;
        int gr = rowbase + r;
        sx[r][k] = (gr < n) ? xd[(long)gr * Dd + k] : 0.f;
    }
    __syncthreads();
    int j = t & 63;
    int r0 = t >> 6;
    for (int rr = r0; rr < ROWS; rr += 4) {
        int gr = rowbase + rr;
        if (gr >= n) continue;
        float acc = sb[j];
#pragma unroll
        for (int k = 0; k < Dm; ++k) acc += sm[rr][k] * sWl[k][j];
#pragma unroll
        for (int k = 0; k < Dd; ++k) acc += sx[rr][k] * sWr[k][j];
        out[(long)gr * H + j] = RELU ? fmaxf(acc, 0.f) : acc;
    }
}

// ---------------- head ----------------

__global__ __launch_bounds__(256) void head_kernel(const float* __restrict__ z_user,
                                                   const float* __restrict__ z_movie,
                                                   const int* __restrict__ lrow,
                                                   const int* __restrict__ lcol,
                                                   const float* __restrict__ Wlin,
                                                   const float* __restrict__ blin,
                                                   float* __restrict__ out, int B) {
    int wave = (blockIdx.x * blockDim.x + threadIdx.x) >> 6;
    int lane = threadIdx.x & 63;
    int nw = (gridDim.x * blockDim.x) >> 6;
    for (int b = wave; b < B; b += nw) {
        int r = lrow[b], c = lcol[b];
        float zu = z_user[(long)r * 64 + lane];
        float zm = z_movie[(long)c * 64 + lane];
        float p0 = zu * Wlin[lane * 2 + 0] + zm * Wlin[(64 + lane) * 2 + 0];
        float p1 = zu * Wlin[lane * 2 + 1] + zm * Wlin[(64 + lane) * 2 + 1];
        for (int s = 32; s; s >>= 1) {
            p0 += __shfl_xor(p0, s, 64);
            p1 += __shfl_xor(p1, s, 64);
        }
        if (lane == 0) {
            float m = p0 + blin[0];
            float x = p1 + blin[1];
            float sp = fmaxf(x, 0.f) + log1pf(expf(-fabsf(x)));
            out[b] = m;
            out[B + b] = sp + 1e-6f;
        }
    }
}

// ---------------- launch ----------------

extern "C" void kernel_launch(void* const* d_in, const int* in_sizes, int n_in,
                              void* d_out, int out_size, void* d_ws, size_t ws_size,
                              hipStream_t stream) {
    const float* x_user  = (const float*)d_in[0];
    const float* x_movie = (const float*)d_in[1];
    const int* src_um = (const int*)d_in[2];
    const int* dst_um = (const int*)d_in[3];
    const int* src_mu = (const int*)d_in[4];
    const int* dst_mu = (const int*)d_in[5];
    const int* lrow = (const int*)d_in[6];
    const int* lcol = (const int*)d_in[7];
    const float* W1_um_l = (const float*)d_in[8];
    const float* b1_um   = (const float*)d_in[9];
    const float* W1_um_r = (const float*)d_in[10];
    const float* W1_mu_l = (const float*)d_in[11];
    const float* b1_mu   = (const float*)d_in[12];
    const float* W1_mu_r = (const float*)d_in[13];
    const float* W2_um_l = (const float*)d_in[14];
    const float* b2_um   = (const float*)d_in[15];
    const float* W2_um_r = (const float*)d_in[16];
    const float* W2_mu_l = (const float*)d_in[17];
    const float* b2_mu   = (const float*)d_in[18];
    const float* W2_mu_r = (const float*)d_in[19];
    const float* W_lin   = (const float*)d_in[20];
    const float* b_lin   = (const float*)d_in[21];
    float* out = (float*)d_out;

    const int E  = in_sizes[2];
    const int B  = in_sizes[6];
    const int NU = in_sizes[0] / 32;   // 100000
    const int NM = in_sizes[1] / 64;   // 20000

    char* wsp = (char*)d_ws;
    size_t o = 0;
    auto alloc = [&](size_t bytes) {
        size_t p = o;
        o += (bytes + 255) & ~(size_t)255;
        return (void*)(wsp + p);
    };
    int* off_um  = (int*)alloc((size_t)(NM + 1) * 4);
    int* off_mu  = (int*)alloc((size_t)(NU + 1) * 4);
    int* bhist_um = (int*)alloc((NB_UM) * 4);
    int* bhist_mu = (int*)alloc((NB_MU) * 4);
    int* boff_um  = (int*)alloc((NB_UM + 1) * 4);
    int* boff_mu  = (int*)alloc((NB_MU + 1) * 4);
    int* bcur_um  = (int*)alloc((NB_UM) * 4);
    int* bcur_mu  = (int*)alloc((NB_MU) * 4);
    int* csr_um = (int*)alloc((size_t)E * 4);
    int* csr_mu = (int*)alloc((size_t)E * 4);
    float* A_m = (float*)alloc((size_t)NM * 64 * 4);   // movie mean / z_movie
    float* A_u = (float*)alloc((size_t)NU * 64 * 4);   // user mean / z_user
    float* H_m = (float*)alloc((size_t)NM * 64 * 4);   // h_movie
    float* H_u = (float*)alloc((size_t)NU * 64 * 4);   // h_user
    (void)ws_size;

    // binning temps alias A_u (consumed before A_u is first written)
    int* tmp_um = (int*)A_u;
    int* tmp_mu = (int*)A_u + E;

    // 1) CSR build (binned counting sort)
    zero_ints<<<8, 256, 0, stream>>>(bhist_um, NB_UM, bhist_mu, NB_MU);
    bucket_hist<<<512, 256, 0, stream>>>(dst_um, dst_mu, bhist_um, bhist_mu, E);
    bucket_scan<<<1, 256, 0, stream>>>(bhist_um, boff_um, bcur_um, NB_UM, off_um, NM, E);
    bucket_scan<<<1, 256, 0, stream>>>(bhist_mu, boff_mu, bcur_mu, NB_MU, off_mu, NU, E);
    bin2<<<2048, 256, 0, stream>>>(src_um, dst_um, src_mu, dst_mu,
                                   bcur_um, bcur_mu, tmp_um, tmp_mu, E);
    scatter_csr<32><<<NB_UM, 256, 0, stream>>>(tmp_um, boff_um, off_um, csr_um, NM);
    scatter_csr<128><<<NB_MU, 256, 0, stream>>>(tmp_mu, boff_mu, off_mu, csr_mu, NU);

    // 2) layer 1
    agg_mean_v<32><<<(NM + 3) / 4, 256, 0, stream>>>(csr_um, off_um, x_user, A_m, NM);
    dense_node<32, 64, true><<<(NM + 15) / 16, 256, 0, stream>>>(A_m, x_movie, W1_um_l, W1_um_r,
                                                                 b1_um, H_m, NM);
    agg_mean_v<64><<<(NU + 3) / 4, 256, 0, stream>>>(csr_mu, off_mu, x_movie, A_u, NU);
    dense_node<64, 32, true><<<(NU + 15) / 16, 256, 0, stream>>>(A_u, x_user, W1_mu_l, W1_mu_r,
                                                                 b1_mu, H_u, NU);

    // 3) layer 2
    agg_mean_v<64><<<(NM + 3) / 4, 256, 0, stream>>>(csr_um, off_um, H_u, A_m, NM);
    dense_node<64, 64, false><<<(NM + 15) / 16, 256, 0, stream>>>(A_m, H_m, W2_um_l, W2_um_r,
                                                                  b2_um, A_m, NM);
    agg_mean_v<64><<<(NU + 3) / 4, 256, 0, stream>>>(csr_mu, off_mu, H_m, A_u, NU);
    dense_node<64, 64, false><<<(NU + 15) / 16, 256, 0, stream>>>(A_u, H_u, W2_mu_l, W2_mu_r,
                                                                  b2_mu, A_u, NU);

    // 4) head
    head_kernel<<<4096, 256, 0, stream>>>(A_u, A_m, lrow, lcol, W_lin, b_lin, out, B);
}

// Round 3
// 580.716 us; speedup vs baseline: 2.0720x; 2.0720x over previous
//
#include <hip/hip_runtime.h>
#include <hip/hip_bf16.h>

// combined bucket space: um buckets [0,625) width 32; mu buckets [625,1407) width 128
#define NB_UM 625
#define NB_MU 782
#define NBALL 1407
#define NBLK 256

// ---------------- pass 1: per-(bucket,block) histogram ----------------

__global__ __launch_bounds__(256) void hist_part(const int* __restrict__ dst_um,
                                                 const int* __restrict__ dst_mu,
                                                 int* __restrict__ histM, int E) {
    __shared__ int h[NBALL];
    for (int i = threadIdx.x; i < NBALL; i += 256) h[i] = 0;
    __syncthreads();
    int blk = blockIdx.x;
    int chunk = (E + NBLK - 1) / NBLK;
    int s = blk * chunk, e = min(E, s + chunk);
    for (int i = s + threadIdx.x; i < e; i += 256) {
        atomicAdd(&h[dst_um[i] >> 5], 1);
        atomicAdd(&h[NB_UM + (dst_mu[i] >> 7)], 1);
    }
    __syncthreads();
    for (int i = threadIdx.x; i < NBALL; i += 256) histM[i * NBLK + blk] = h[i];
}

// ---------------- pass 2: per-bucket wave scan over blocks ----------------

__global__ __launch_bounds__(256) void bucket_totals(int* __restrict__ histM,
                                                     int* __restrict__ btot, int nball) {
    int w = (blockIdx.x * blockDim.x + threadIdx.x) >> 6;
    int lane = threadIdx.x & 63;
    if (w >= nball) return;
    int* row = histM + w * NBLK;
    int v[4];
    int s = 0;
#pragma unroll
    for (int i = 0; i < 4; i++) {
        int c = row[lane * 4 + i];
        v[i] = s;
        s += c;
    }
    int incl = s;
    for (int d = 1; d < 64; d <<= 1) {
        int y = __shfl_up(incl, d, 64);
        if (lane >= d) incl += y;
    }
    int excl = incl - s;
#pragma unroll
    for (int i = 0; i < 4; i++) row[lane * 4 + i] = excl + v[i];
    if (lane == 63) btot[w] = incl;
}

// ---------------- pass 3: scan bucket totals ----------------

__global__ __launch_bounds__(256) void boff_scan(const int* __restrict__ btot,
                                                 int* __restrict__ boff, int nball,
                                                 int* __restrict__ off_um, int NM,
                                                 int* __restrict__ off_mu, int NU, int E) {
    __shared__ int sdata[256];
    int t = threadIdx.x;
    int v[8];
    int sum = 0;
#pragma unroll
    for (int i = 0; i < 8; i++) {
        int idx = t * 8 + i;
        int c = (idx < nball) ? btot[idx] : 0;
        v[i] = sum;
        sum += c;
    }
    sdata[t] = sum;
    __syncthreads();
    for (int s = 1; s < 256; s <<= 1) {
        int y = (t >= s) ? sdata[t - s] : 0;
        __syncthreads();
        sdata[t] += y;
        __syncthreads();
    }
    int base = (t == 0) ? 0 : sdata[t - 1];
#pragma unroll
    for (int i = 0; i < 8; i++) {
        int idx = t * 8 + i;
        if (idx < nball) boff[idx] = base + v[i];
    }
    if (t == 0) {
        boff[nball] = 2 * E;
        off_um[NM] = E;
        off_mu[NU] = E;
    }
}

// ---------------- pass 4: finalize off_mat ----------------

__global__ __launch_bounds__(256) void add_boff(int* __restrict__ histM,
                                                const int* __restrict__ boff, int n) {
    int st = gridDim.x * blockDim.x;
    for (int i = blockIdx.x * blockDim.x + threadIdx.x; i < n; i += st)
        histM[i] += boff[i >> 8];  // NBLK==256
}

// ---------------- pass 5: partition (block-private cursors in LDS) ----------------

__global__ __launch_bounds__(256) void partition2(const int* __restrict__ src_um,
                                                  const int* __restrict__ dst_um,
                                                  const int* __restrict__ src_mu,
                                                  const int* __restrict__ dst_mu,
                                                  const int* __restrict__ histM,
                                                  int* __restrict__ tmp, int E) {
    __shared__ int cur[NBALL];
    int blk = blockIdx.x;
    for (int i = threadIdx.x; i < NBALL; i += 256) cur[i] = histM[i * NBLK + blk];
    __syncthreads();
    int chunk = (E + NBLK - 1) / NBLK;
    int s = blk * chunk, e = min(E, s + chunk);
    for (int i = s + threadIdx.x; i < e; i += 256) {
        int d = dst_um[i];
        int p = atomicAdd(&cur[d >> 5], 1);
        tmp[p] = src_um[i] | ((d & 31) << 20);
        int d2 = dst_mu[i];
        int q = atomicAdd(&cur[NB_UM + (d2 >> 7)], 1);
        tmp[q] = src_mu[i] | ((d2 & 127) << 20);
    }
}

// ---------------- pass 6: per-bucket CSR scatter ----------------

template <int W>
__global__ __launch_bounds__(256) void scatter_csr(const int* __restrict__ tmp,
                                                   const int* __restrict__ boff,
                                                   int* __restrict__ off,
                                                   int* __restrict__ csr, int n, int sub) {
    __shared__ int lcnt[W];
    __shared__ int lcur[W];
    int b = blockIdx.x;
    int t = threadIdx.x;
    int s = boff[b], e = boff[b + 1];
    if (t < W) lcnt[t] = 0;
    __syncthreads();
    for (int i = s + t; i < e; i += 256) atomicAdd(&lcnt[tmp[i] >> 20], 1);
    __syncthreads();
    if (t == 0) {
        int acc = s;
        for (int j = 0; j < W; j++) {
            lcur[j] = acc;
            acc += lcnt[j];
        }
    }
    __syncthreads();
    int base = b * W;
    if (t < W && base + t < n) off[base + t] = lcur[t] - sub;
    __syncthreads();
    for (int i = s + t; i < e; i += 256) {
        int v = tmp[i];
        int p = atomicAdd(&lcur[v >> 20], 1);
        csr[p - sub] = v & 0xFFFFF;
    }
}

// ---------------- segment mean (gather, one wave per dst row) ----------------

template <int D>
__global__ __launch_bounds__(256) void agg_mean_v(const int* __restrict__ csr,
                                                  const int* __restrict__ off,
                                                  const float* __restrict__ x,
                                                  float* __restrict__ out, int nrows) {
    constexpr int LPE = D / 4;
    constexpr int GRP = 64 / LPE;
    int wave = (blockIdx.x * blockDim.x + threadIdx.x) >> 6;
    int lane = threadIdx.x & 63;
    int nwaves = (gridDim.x * blockDim.x) >> 6;
    int g = lane / LPE;
    int cl = lane % LPE;
    for (int row = wave; row < nrows; row += nwaves) {
        int s = off[row], e = off[row + 1];
        float4 acc = make_float4(0.f, 0.f, 0.f, 0.f);
        for (int k = s + g; k < e; k += GRP) {
            int idx = csr[k];
            const float4 v = *(const float4*)&x[(long)idx * D + cl * 4];
            acc.x += v.x; acc.y += v.y; acc.z += v.z; acc.w += v.w;
        }
        for (int m = LPE; m < 64; m <<= 1) {
            acc.x += __shfl_xor(acc.x, m, 64);
            acc.y += __shfl_xor(acc.y, m, 64);
            acc.z += __shfl_xor(acc.z, m, 64);
            acc.w += __shfl_xor(acc.w, m, 64);
        }
        if (g == 0) {
            float inv = 1.0f / fmaxf((float)(e - s), 1.0f);
            float4 r = make_float4(acc.x * inv, acc.y * inv, acc.z * inv, acc.w * inv);
            *(float4*)&out[(long)row * D + cl * 4] = r;
        }
    }
}

// ---------------- per-node dense: out = act(mean@Wl + b + xd@Wr) ----------------

template <int Dm, int Dd, bool RELU>
__global__ __launch_bounds__(256) void dense_node(const float* __restrict__ mean,
                                                  const float* __restrict__ xd,
                                                  const float* __restrict__ Wl,
                                                  const float* __restrict__ Wr,
                                                  const float* __restrict__ bias,
                                                  float* __restrict__ out, int n) {
    constexpr int H = 64;
    constexpr int ROWS = 16;
    __shared__ float sWl[Dm][H];
    __shared__ float sWr[Dd][H];
    __shared__ float sb[H];
    __shared__ float sm[ROWS][Dm];
    __shared__ float sx[ROWS][Dd];
    int t = threadIdx.x;
    for (int i = t; i < Dm * H; i += 256) sWl[i / H][i % H] = Wl[i];
    for (int i = t; i < Dd * H; i += 256) sWr[i / H][i % H] = Wr[i];
    if (t < H) sb[t] = bias[t];
    int rowbase = blockIdx.x * ROWS;
    for (int i = t; i < ROWS * Dm; i += 256) {
        int r = i / Dm, k = i % Dm;
        int gr = rowbase + r;
        sm[r][k] = (gr < n) ? mean[(long)gr * Dm + k] : 0.f;
    }
    for (int i = t; i < ROWS * Dd; i += 256) {
        int r = i / Dd, k = i % Dd;
        int gr = rowbase + r;
        sx[r][k] = (gr < n) ? xd[(long)gr * Dd + k] : 0.f;
    }
    __syncthreads();
    int j = t & 63;
    int r0 = t >> 6;
    for (int rr = r0; rr < ROWS; rr += 4) {
        int gr = rowbase + rr;
        if (gr >= n) continue;
        float acc = sb[j];
#pragma unroll
        for (int k = 0; k < Dm; ++k) acc += sm[rr][k] * sWl[k][j];
#pragma unroll
        for (int k = 0; k < Dd; ++k) acc += sx[rr][k] * sWr[k][j];
        out[(long)gr * H + j] = RELU ? fmaxf(acc, 0.f) : acc;
    }
}

// ---------------- head ----------------

__global__ __launch_bounds__(256) void head_kernel(const float* __restrict__ z_user,
                                                   const float* __restrict__ z_movie,
                                                   const int* __restrict__ lrow,
                                                   const int* __restrict__ lcol,
                                                   const float* __restrict__ Wlin,
                                                   const float* __restrict__ blin,
                                                   float* __restrict__ out, int B) {
    int wave = (blockIdx.x * blockDim.x + threadIdx.x) >> 6;
    int lane = threadIdx.x & 63;
    int nw = (gridDim.x * blockDim.x) >> 6;
    for (int b = wave; b < B; b += nw) {
        int r = lrow[b], c = lcol[b];
        float zu = z_user[(long)r * 64 + lane];
        float zm = z_movie[(long)c * 64 + lane];
        float p0 = zu * Wlin[lane * 2 + 0] + zm * Wlin[(64 + lane) * 2 + 0];
        float p1 = zu * Wlin[lane * 2 + 1] + zm * Wlin[(64 + lane) * 2 + 1];
        for (int s = 32; s; s >>= 1) {
            p0 += __shfl_xor(p0, s, 64);
            p1 += __shfl_xor(p1, s, 64);
        }
        if (lane == 0) {
            float m = p0 + blin[0];
            float x = p1 + blin[1];
            float sp = fmaxf(x, 0.f) + log1pf(expf(-fabsf(x)));
            out[b] = m;
            out[B + b] = sp + 1e-6f;
        }
    }
}

// ---------------- launch ----------------

extern "C" void kernel_launch(void* const* d_in, const int* in_sizes, int n_in,
                              void* d_out, int out_size, void* d_ws, size_t ws_size,
                              hipStream_t stream) {
    const float* x_user  = (const float*)d_in[0];
    const float* x_movie = (const float*)d_in[1];
    const int* src_um = (const int*)d_in[2];
    const int* dst_um = (const int*)d_in[3];
    const int* src_mu = (const int*)d_in[4];
    const int* dst_mu = (const int*)d_in[5];
    const int* lrow = (const int*)d_in[6];
    const int* lcol = (const int*)d_in[7];
    const float* W1_um_l = (const float*)d_in[8];
    const float* b1_um   = (const float*)d_in[9];
    const float* W1_um_r = (const float*)d_in[10];
    const float* W1_mu_l = (const float*)d_in[11];
    const float* b1_mu   = (const float*)d_in[12];
    const float* W1_mu_r = (const float*)d_in[13];
    const float* W2_um_l = (const float*)d_in[14];
    const float* b2_um   = (const float*)d_in[15];
    const float* W2_um_r = (const float*)d_in[16];
    const float* W2_mu_l = (const float*)d_in[17];
    const float* b2_mu   = (const float*)d_in[18];
    const float* W2_mu_r = (const float*)d_in[19];
    const float* W_lin   = (const float*)d_in[20];
    const float* b_lin   = (const float*)d_in[21];
    float* out = (float*)d_out;

    const int E  = in_sizes[2];
    const int B  = in_sizes[6];
    const int NU = in_sizes[0] / 32;   // 100000
    const int NM = in_sizes[1] / 64;   // 20000

    char* wsp = (char*)d_ws;
    size_t o = 0;
    auto alloc = [&](size_t bytes) {
        size_t p = o;
        o += (bytes + 255) & ~(size_t)255;
        return (void*)(wsp + p);
    };
    int* off_um = (int*)alloc((size_t)(NM + 1) * 4);
    int* off_mu = (int*)alloc((size_t)(NU + 1) * 4);
    int* btot   = (int*)alloc((NBALL) * 4);
    int* boff   = (int*)alloc((NBALL + 1) * 4);
    int* csr_um = (int*)alloc((size_t)E * 4);
    int* csr_mu = (int*)alloc((size_t)E * 4);
    float* A_m = (float*)alloc((size_t)NM * 64 * 4);   // movie mean / z_movie
    float* A_u = (float*)alloc((size_t)NU * 64 * 4);   // user mean / z_user
    float* H_m = (float*)alloc((size_t)NM * 64 * 4);   // h_movie
    float* H_u = (float*)alloc((size_t)NU * 64 * 4);   // h_user
    (void)ws_size;

    // aliases: consumed before their hosts are first written
    int* tmp   = (int*)A_u;   // [2E] ints = 16 MB <= 25.6 MB; dead after scatter_csr
    int* histM = (int*)H_m;   // [NBALL*NBLK] = 1.44 MB; dead after partition2

    // 1) CSR build (block-private radix partition)
    hist_part<<<NBLK, 256, 0, stream>>>(dst_um, dst_mu, histM, E);
    bucket_totals<<<(NBALL + 3) / 4, 256, 0, stream>>>(histM, btot, NBALL);
    boff_scan<<<1, 256, 0, stream>>>(btot, boff, NBALL, off_um, NM, off_mu, NU, E);
    add_boff<<<352, 256, 0, stream>>>(histM, boff, NBALL * NBLK);
    partition2<<<NBLK, 256, 0, stream>>>(src_um, dst_um, src_mu, dst_mu, histM, tmp, E);
    scatter_csr<32><<<NB_UM, 256, 0, stream>>>(tmp, boff, off_um, csr_um, NM, 0);
    scatter_csr<128><<<NB_MU, 256, 0, stream>>>(tmp, boff + NB_UM, off_mu, csr_mu, NU, E);

    // 2) layer 1
    agg_mean_v<32><<<(NM + 3) / 4, 256, 0, stream>>>(csr_um, off_um, x_user, A_m, NM);
    dense_node<32, 64, true><<<(NM + 15) / 16, 256, 0, stream>>>(A_m, x_movie, W1_um_l, W1_um_r,
                                                                 b1_um, H_m, NM);
    agg_mean_v<64><<<(NU + 3) / 4, 256, 0, stream>>>(csr_mu, off_mu, x_movie, A_u, NU);
    dense_node<64, 32, true><<<(NU + 15) / 16, 256, 0, stream>>>(A_u, x_user, W1_mu_l, W1_mu_r,
                                                                 b1_mu, H_u, NU);

    // 3) layer 2
    agg_mean_v<64><<<(NM + 3) / 4, 256, 0, stream>>>(csr_um, off_um, H_u, A_m, NM);
    dense_node<64, 64, false><<<(NM + 15) / 16, 256, 0, stream>>>(A_m, H_m, W2_um_l, W2_um_r,
                                                                  b2_um, A_m, NM);
    agg_mean_v<64><<<(NU + 3) / 4, 256, 0, stream>>>(csr_mu, off_mu, H_m, A_u, NU);
    dense_node<64, 64, false><<<(NU + 15) / 16, 256, 0, stream>>>(A_u, H_u, W2_mu_l, W2_mu_r,
                                                                  b2_mu, A_u, NU);

    // 4) head
    head_kernel<<<4096, 256, 0, stream>>>(A_u, A_m, lrow, lcol, W_lin, b_lin, out, B);
}

// Round 4
// 472.256 us; speedup vs baseline: 2.5478x; 1.2297x over previous
//
#include <hip/hip_runtime.h>
#include <hip/hip_bf16.h>

// combined bucket space: um buckets [0,625) width 32; mu buckets [625,1407) width 128
#define NB_UM 625
#define NB_MU 782
#define NBALL 1407
#define NBLK 256

// ---------------- pass 1: per-(bucket,block) histogram ----------------

__global__ __launch_bounds__(256) void hist_part(const int* __restrict__ dst_um,
                                                 const int* __restrict__ dst_mu,
                                                 int* __restrict__ histM, int E) {
    __shared__ int h[NBALL];
    for (int i = threadIdx.x; i < NBALL; i += 256) h[i] = 0;
    __syncthreads();
    int blk = blockIdx.x;
    int chunk = (E + NBLK - 1) / NBLK;
    int s = blk * chunk, e = min(E, s + chunk);
    for (int i = s + threadIdx.x; i < e; i += 256) {
        atomicAdd(&h[dst_um[i] >> 5], 1);
        atomicAdd(&h[NB_UM + (dst_mu[i] >> 7)], 1);
    }
    __syncthreads();
    for (int i = threadIdx.x; i < NBALL; i += 256) histM[i * NBLK + blk] = h[i];
}

// ---------------- pass 2: per-bucket wave scan over blocks ----------------

__global__ __launch_bounds__(256) void bucket_totals(int* __restrict__ histM,
                                                     int* __restrict__ btot, int nball) {
    int w = (blockIdx.x * blockDim.x + threadIdx.x) >> 6;
    int lane = threadIdx.x & 63;
    if (w >= nball) return;
    int* row = histM + w * NBLK;
    int v[4];
    int s = 0;
#pragma unroll
    for (int i = 0; i < 4; i++) {
        int c = row[lane * 4 + i];
        v[i] = s;
        s += c;
    }
    int incl = s;
    for (int d = 1; d < 64; d <<= 1) {
        int y = __shfl_up(incl, d, 64);
        if (lane >= d) incl += y;
    }
    int excl = incl - s;
#pragma unroll
    for (int i = 0; i < 4; i++) row[lane * 4 + i] = excl + v[i];
    if (lane == 63) btot[w] = incl;
}

// ---------------- pass 3: scan bucket totals ----------------

__global__ __launch_bounds__(256) void boff_scan(const int* __restrict__ btot,
                                                 int* __restrict__ boff, int nball,
                                                 int* __restrict__ off_um, int NM,
                                                 int* __restrict__ off_mu, int NU, int E) {
    __shared__ int sdata[256];
    int t = threadIdx.x;
    int v[8];
    int sum = 0;
#pragma unroll
    for (int i = 0; i < 8; i++) {
        int idx = t * 8 + i;
        int c = (idx < nball) ? btot[idx] : 0;
        v[i] = sum;
        sum += c;
    }
    sdata[t] = sum;
    __syncthreads();
    for (int s = 1; s < 256; s <<= 1) {
        int y = (t >= s) ? sdata[t - s] : 0;
        __syncthreads();
        sdata[t] += y;
        __syncthreads();
    }
    int base = (t == 0) ? 0 : sdata[t - 1];
#pragma unroll
    for (int i = 0; i < 8; i++) {
        int idx = t * 8 + i;
        if (idx < nball) boff[idx] = base + v[i];
    }
    if (t == 0) {
        boff[nball] = 2 * E;
        off_um[NM] = E;
        off_mu[NU] = E;
    }
}

// ---------------- pass 4: finalize off_mat ----------------

__global__ __launch_bounds__(256) void add_boff(int* __restrict__ histM,
                                                const int* __restrict__ boff, int n) {
    int st = gridDim.x * blockDim.x;
    for (int i = blockIdx.x * blockDim.x + threadIdx.x; i < n; i += st)
        histM[i] += boff[i >> 8];  // NBLK==256
}

// ---------------- pass 5: partition (block-private cursors in LDS) ----------------

__global__ __launch_bounds__(256) void partition2(const int* __restrict__ src_um,
                                                  const int* __restrict__ dst_um,
                                                  const int* __restrict__ src_mu,
                                                  const int* __restrict__ dst_mu,
                                                  const int* __restrict__ histM,
                                                  int* __restrict__ tmp, int E) {
    __shared__ int cur[NBALL];
    int blk = blockIdx.x;
    for (int i = threadIdx.x; i < NBALL; i += 256) cur[i] = histM[i * NBLK + blk];
    __syncthreads();
    int chunk = (E + NBLK - 1) / NBLK;
    int s = blk * chunk, e = min(E, s + chunk);
    for (int i = s + threadIdx.x; i < e; i += 256) {
        int d = dst_um[i];
        int p = atomicAdd(&cur[d >> 5], 1);
        tmp[p] = src_um[i] | ((d & 31) << 20);
        int d2 = dst_mu[i];
        int q = atomicAdd(&cur[NB_UM + (d2 >> 7)], 1);
        tmp[q] = src_mu[i] | ((d2 & 127) << 20);
    }
}

// ---------------- pass 6: per-bucket CSR scatter ----------------

template <int W>
__global__ __launch_bounds__(256) void scatter_csr(const int* __restrict__ tmp,
                                                   const int* __restrict__ boff,
                                                   int* __restrict__ off,
                                                   int* __restrict__ csr, int n, int sub) {
    __shared__ int lcnt[W];
    __shared__ int lcur[W];
    int b = blockIdx.x;
    int t = threadIdx.x;
    int s = boff[b], e = boff[b + 1];
    if (t < W) lcnt[t] = 0;
    __syncthreads();
    for (int i = s + t; i < e; i += 256) atomicAdd(&lcnt[tmp[i] >> 20], 1);
    __syncthreads();
    if (t == 0) {
        int acc = s;
        for (int j = 0; j < W; j++) {
            lcur[j] = acc;
            acc += lcnt[j];
        }
    }
    __syncthreads();
    int base = b * W;
    if (t < W && base + t < n) off[base + t] = lcur[t] - sub;
    __syncthreads();
    for (int i = s + t; i < e; i += 256) {
        int v = tmp[i];
        int p = atomicAdd(&lcur[v >> 20], 1);
        csr[p - sub] = v & 0xFFFFF;
    }
}

// ---------------- segment mean (gather, one wave per dst row) ----------------

template <int D>
__global__ __launch_bounds__(256) void agg_mean_v(const int* __restrict__ csr,
                                                  const int* __restrict__ off,
                                                  const float* __restrict__ x,
                                                  float* __restrict__ out, int nrows) {
    constexpr int LPE = D / 4;
    constexpr int GRP = 64 / LPE;
    int wave = (blockIdx.x * blockDim.x + threadIdx.x) >> 6;
    int lane = threadIdx.x & 63;
    int nwaves = (gridDim.x * blockDim.x) >> 6;
    int g = lane / LPE;
    int cl = lane % LPE;
    for (int row = wave; row < nrows; row += nwaves) {
        int s = off[row], e = off[row + 1];
        float4 acc = make_float4(0.f, 0.f, 0.f, 0.f);
        for (int k = s + g; k < e; k += GRP) {
            int idx = csr[k];
            const float4 v = *(const float4*)&x[(long)idx * D + cl * 4];
            acc.x += v.x; acc.y += v.y; acc.z += v.z; acc.w += v.w;
        }
        for (int m = LPE; m < 64; m <<= 1) {
            acc.x += __shfl_xor(acc.x, m, 64);
            acc.y += __shfl_xor(acc.y, m, 64);
            acc.z += __shfl_xor(acc.z, m, 64);
            acc.w += __shfl_xor(acc.w, m, 64);
        }
        if (g == 0) {
            float inv = 1.0f / fmaxf((float)(e - s), 1.0f);
            float4 r = make_float4(acc.x * inv, acc.y * inv, acc.z * inv, acc.w * inv);
            *(float4*)&out[(long)row * D + cl * 4] = r;
        }
    }
}

// ---------------- dense: out = act([mean|xd] @ [Wl;Wr] + b) ----------------
// 64 rows x 64 cols per block, 256 threads, 4x4 register micro-tile.
// K = Dm + Dd (96 or 128). LDS: A tile [64][K+4], W [K][68], bias.

template <int Dm, int Dd, bool RELU>
__global__ __launch_bounds__(256) void dense_gemm(const float* __restrict__ mean,
                                                  const float* __restrict__ xd,
                                                  const float* __restrict__ Wl,
                                                  const float* __restrict__ Wr,
                                                  const float* __restrict__ bias,
                                                  float* __restrict__ out, int n) {
    constexpr int K = Dm + Dd;
    __shared__ float sA[64][K + 4];
    __shared__ float sW[K][68];
    __shared__ float sb[64];
    int t = threadIdx.x;
    int R0 = blockIdx.x * 64;

    // stage W ([Wl;Wr] stacked), float4 quads
    for (int i = t; i < K * 16; i += 256) {
        int r = i >> 4, c = (i & 15) * 4;
        float4 v = (r < Dm) ? *(const float4*)&Wl[r * 64 + c]
                            : *(const float4*)&Wr[(r - Dm) * 64 + c];
        sW[r][c + 0] = v.x; sW[r][c + 1] = v.y; sW[r][c + 2] = v.z; sW[r][c + 3] = v.w;
    }
    if (t < 64) sb[t] = bias[t];
    // stage A tile: row r cols [0,Dm) from mean, [Dm,K) from xd
    constexpr int QR = K / 4;  // quads per row
    for (int i = t; i < 64 * QR; i += 256) {
        int r = i / QR, c = (i % QR) * 4;
        int gr = R0 + r;
        float4 v = make_float4(0.f, 0.f, 0.f, 0.f);
        if (gr < n)
            v = (c < Dm) ? *(const float4*)&mean[(long)gr * Dm + c]
                         : *(const float4*)&xd[(long)gr * Dd + (c - Dm)];
        sA[r][c + 0] = v.x; sA[r][c + 1] = v.y; sA[r][c + 2] = v.z; sA[r][c + 3] = v.w;
    }
    __syncthreads();

    int tx = t & 15, ty = t >> 4;       // tx: col quad, ty: row quad
    int c0 = tx * 4, r0 = ty * 4;
    float acc[4][4];
    float4 bb = *(float4*)&sb[c0];
#pragma unroll
    for (int i = 0; i < 4; i++) {
        acc[i][0] = bb.x; acc[i][1] = bb.y; acc[i][2] = bb.z; acc[i][3] = bb.w;
    }
#pragma unroll 4
    for (int k = 0; k < K; k += 4) {
        float4 a[4], b[4];
#pragma unroll
        for (int i = 0; i < 4; i++) a[i] = *(float4*)&sA[r0 + i][k];
#pragma unroll
        for (int kk = 0; kk < 4; kk++) b[kk] = *(float4*)&sW[k + kk][c0];
#pragma unroll
        for (int i = 0; i < 4; i++) {
            acc[i][0] += a[i].x * b[0].x + a[i].y * b[1].x + a[i].z * b[2].x + a[i].w * b[3].x;
            acc[i][1] += a[i].x * b[0].y + a[i].y * b[1].y + a[i].z * b[2].y + a[i].w * b[3].y;
            acc[i][2] += a[i].x * b[0].z + a[i].y * b[1].z + a[i].z * b[2].z + a[i].w * b[3].z;
            acc[i][3] += a[i].x * b[0].w + a[i].y * b[1].w + a[i].z * b[2].w + a[i].w * b[3].w;
        }
    }
#pragma unroll
    for (int i = 0; i < 4; i++) {
        int gr = R0 + r0 + i;
        if (gr >= n) continue;
        float4 r;
        if (RELU) {
            r = make_float4(fmaxf(acc[i][0], 0.f), fmaxf(acc[i][1], 0.f),
                            fmaxf(acc[i][2], 0.f), fmaxf(acc[i][3], 0.f));
        } else {
            r = make_float4(acc[i][0], acc[i][1], acc[i][2], acc[i][3]);
        }
        *(float4*)&out[(long)gr * 64 + c0] = r;
    }
}

// ---------------- head ----------------

__global__ __launch_bounds__(256) void head_kernel(const float* __restrict__ z_user,
                                                   const float* __restrict__ z_movie,
                                                   const int* __restrict__ lrow,
                                                   const int* __restrict__ lcol,
                                                   const float* __restrict__ Wlin,
                                                   const float* __restrict__ blin,
                                                   float* __restrict__ out, int B) {
    int wave = (blockIdx.x * blockDim.x + threadIdx.x) >> 6;
    int lane = threadIdx.x & 63;
    int nw = (gridDim.x * blockDim.x) >> 6;
    for (int b = wave; b < B; b += nw) {
        int r = lrow[b], c = lcol[b];
        float zu = z_user[(long)r * 64 + lane];
        float zm = z_movie[(long)c * 64 + lane];
        float p0 = zu * Wlin[lane * 2 + 0] + zm * Wlin[(64 + lane) * 2 + 0];
        float p1 = zu * Wlin[lane * 2 + 1] + zm * Wlin[(64 + lane) * 2 + 1];
        for (int s = 32; s; s >>= 1) {
            p0 += __shfl_xor(p0, s, 64);
            p1 += __shfl_xor(p1, s, 64);
        }
        if (lane == 0) {
            float m = p0 + blin[0];
            float x = p1 + blin[1];
            float sp = fmaxf(x, 0.f) + log1pf(expf(-fabsf(x)));
            out[b] = m;
            out[B + b] = sp + 1e-6f;
        }
    }
}

// ---------------- launch ----------------

extern "C" void kernel_launch(void* const* d_in, const int* in_sizes, int n_in,
                              void* d_out, int out_size, void* d_ws, size_t ws_size,
                              hipStream_t stream) {
    const float* x_user  = (const float*)d_in[0];
    const float* x_movie = (const float*)d_in[1];
    const int* src_um = (const int*)d_in[2];
    const int* dst_um = (const int*)d_in[3];
    const int* src_mu = (const int*)d_in[4];
    const int* dst_mu = (const int*)d_in[5];
    const int* lrow = (const int*)d_in[6];
    const int* lcol = (const int*)d_in[7];
    const float* W1_um_l = (const float*)d_in[8];
    const float* b1_um   = (const float*)d_in[9];
    const float* W1_um_r = (const float*)d_in[10];
    const float* W1_mu_l = (const float*)d_in[11];
    const float* b1_mu   = (const float*)d_in[12];
    const float* W1_mu_r = (const float*)d_in[13];
    const float* W2_um_l = (const float*)d_in[14];
    const float* b2_um   = (const float*)d_in[15];
    const float* W2_um_r = (const float*)d_in[16];
    const float* W2_mu_l = (const float*)d_in[17];
    const float* b2_mu   = (const float*)d_in[18];
    const float* W2_mu_r = (const float*)d_in[19];
    const float* W_lin   = (const float*)d_in[20];
    const float* b_lin   = (const float*)d_in[21];
    float* out = (float*)d_out;

    const int E  = in_sizes[2];
    const int B  = in_sizes[6];
    const int NU = in_sizes[0] / 32;   // 100000
    const int NM = in_sizes[1] / 64;   // 20000

    char* wsp = (char*)d_ws;
    size_t o = 0;
    auto alloc = [&](size_t bytes) {
        size_t p = o;
        o += (bytes + 255) & ~(size_t)255;
        return (void*)(wsp + p);
    };
    int* off_um = (int*)alloc((size_t)(NM + 1) * 4);
    int* off_mu = (int*)alloc((size_t)(NU + 1) * 4);
    int* btot   = (int*)alloc((NBALL) * 4);
    int* boff   = (int*)alloc((NBALL + 1) * 4);
    int* csr_um = (int*)alloc((size_t)E * 4);
    int* csr_mu = (int*)alloc((size_t)E * 4);
    float* A_m = (float*)alloc((size_t)NM * 64 * 4);   // movie mean / z_movie
    float* A_u = (float*)alloc((size_t)NU * 64 * 4);   // user mean / z_user
    float* H_m = (float*)alloc((size_t)NM * 64 * 4);   // h_movie
    float* H_u = (float*)alloc((size_t)NU * 64 * 4);   // h_user
    (void)ws_size;

    // aliases: consumed before their hosts are first written
    int* tmp   = (int*)A_u;   // [2E] ints = 16 MB <= 25.6 MB; dead after scatter_csr
    int* histM = (int*)H_m;   // [NBALL*NBLK] = 1.44 MB; dead after partition2

    // 1) CSR build (block-private radix partition)
    hist_part<<<NBLK, 256, 0, stream>>>(dst_um, dst_mu, histM, E);
    bucket_totals<<<(NBALL + 3) / 4, 256, 0, stream>>>(histM, btot, NBALL);
    boff_scan<<<1, 256, 0, stream>>>(btot, boff, NBALL, off_um, NM, off_mu, NU, E);
    add_boff<<<352, 256, 0, stream>>>(histM, boff, NBALL * NBLK);
    partition2<<<NBLK, 256, 0, stream>>>(src_um, dst_um, src_mu, dst_mu, histM, tmp, E);
    scatter_csr<32><<<NB_UM, 256, 0, stream>>>(tmp, boff, off_um, csr_um, NM, 0);
    scatter_csr<128><<<NB_MU, 256, 0, stream>>>(tmp, boff + NB_UM, off_mu, csr_mu, NU, E);

    // 2) layer 1
    agg_mean_v<32><<<(NM + 3) / 4, 256, 0, stream>>>(csr_um, off_um, x_user, A_m, NM);
    dense_gemm<32, 64, true><<<(NM + 63) / 64, 256, 0, stream>>>(A_m, x_movie, W1_um_l, W1_um_r,
                                                                 b1_um, H_m, NM);
    agg_mean_v<64><<<(NU + 3) / 4, 256, 0, stream>>>(csr_mu, off_mu, x_movie, A_u, NU);
    dense_gemm<64, 32, true><<<(NU + 63) / 64, 256, 0, stream>>>(A_u, x_user, W1_mu_l, W1_mu_r,
                                                                 b1_mu, H_u, NU);

    // 3) layer 2 (in-place over the mean buffers; block stages its rows before writing)
    agg_mean_v<64><<<(NM + 3) / 4, 256, 0, stream>>>(csr_um, off_um, H_u, A_m, NM);
    dense_gemm<64, 64, false><<<(NM + 63) / 64, 256, 0, stream>>>(A_m, H_m, W2_um_l, W2_um_r,
                                                                  b2_um, A_m, NM);
    agg_mean_v<64><<<(NU + 3) / 4, 256, 0, stream>>>(csr_mu, off_mu, H_m, A_u, NU);
    dense_gemm<64, 64, false><<<(NU + 63) / 64, 256, 0, stream>>>(A_u, H_u, W2_mu_l, W2_mu_r,
                                                                  b2_mu, A_u, NU);

    // 4) head
    head_kernel<<<4096, 256, 0, stream>>>(A_u, A_m, lrow, lcol, W_lin, b_lin, out, B);
}